// Round 9
// baseline (43.373 us; speedup 1.0000x reference)
//
#include <hip/hip_runtime.h>
#include <hip/hip_fp16.h>

// HalutMatmul forward on MI355X.
// Per row n: h[c][p] = sum_d I[n, c*9+d] * A[c][d][p]   (c=0..15, p=0..3)
//            code_c  = 4-level tree descent: bit_l = (h[c][l] > T[c*15 + node_l])
//            out[n][m] = sum_c L[m][c][code_c]
//
// Round-9: LDS-pipe de-duplication. Rounds 3-8 all ~30us; corrected pipe model
// shows the floor was 400+ wave-redundant ds_read_b128/row re-reading the SAME
// 6.5KB of A/T constants. Fix: prep kernel converts A,T -> f64 in d_ws; main
// kernel reads them with wave-uniform compile-time indices -> compiler emits
// s_load to SGPRs (scalar cache), v_fma_f64 with SGPR-pair operand. LDS now
// holds only the 32KB f16 LUT; math order identical -> codes bit-identical.

#define NROWS (1024 * 128)

// ---- prep: A (576 f32) and T (240 f32) -> f64 in workspace ----
__global__ __launch_bounds__(1024) void halut_prep(
    const float* __restrict__ A,
    const float* __restrict__ T,
    double* __restrict__ W)
{
    const int t = threadIdx.x;
    if (t < 576) W[t] = (double)A[t];
    if (t >= 576 && t < 816) W[t] = (double)T[t - 576];
}

// ---- main ----
__global__ __launch_bounds__(256, 4) void halut_fwd(
    const float* __restrict__ I,
    const double* __restrict__ W,     // [0,576) = A f64, [576,816) = T f64
    const float* __restrict__ L,
    float* __restrict__ out)
{
    // 32 KiB: f16 LUT uint4[q=0..7][col=0..255], col = c*16+p; uint4 dword e
    // holds m = (8q+2e, 8q+2e+1). Reused as float[128][64] epilogue staging.
    __shared__ uint32_t sBuf[8192];

    const int tid = threadIdx.x;

    {   // ---- stage LUT: thread t owns column col = t; coalesced loads ----
        uint4* lut4 = (uint4*)sBuf;
        #pragma unroll
        for (int q = 0; q < 8; ++q) {
            uint32_t w[4];
            #pragma unroll
            for (int e = 0; e < 4; ++e) {
                const float fa = L[(8 * q + 2 * e)     * 256 + tid];
                const float fb = L[(8 * q + 2 * e + 1) * 256 + tid];
                w[e] = ((uint32_t)__half_as_ushort(__float2half_rn(fb)) << 16)
                     |  (uint32_t)__half_as_ushort(__float2half_rn(fa));
            }
            lut4[q * 256 + tid] = make_uint4(w[0], w[1], w[2], w[3]);
        }
    }
    __syncthreads();

    const double* __restrict__ Aw = W;        // uniform, compile-time indexed
    const double* __restrict__ Tw = W + 576;  // -> s_load / scalar cache

    const int row = blockIdx.x * 256 + tid;   // 1 thread = 1 row
    const float* rp = I + (size_t)row * 144;

    __half2 acc2[32];
    #pragma unroll
    for (int k = 0; k < 32; ++k) acc2[k] = __floats2half2_rn(0.f, 0.f);

    const uint4* lut4 = (const uint4*)sBuf;

    #pragma unroll
    for (int g = 0; g < 4; ++g) {             // 4 codebooks per group
        float4 buf[9];
        {
            const float4* rv = (const float4*)(rp + g * 36);  // 144B-aligned
            #pragma unroll
            for (int i = 0; i < 9; ++i) buf[i] = rv[i];
        }
        const float* bf = (const float*)buf;

        #pragma unroll
        for (int cc = 0; cc < 4; ++cc) {
            const int c = g * 4 + cc;         // literal after unroll
            // ---- f64 hash; A from SGPRs (scalar loads), same FMA order ----
            double h0 = 0.0, h1 = 0.0, h2 = 0.0, h3 = 0.0;
            #pragma unroll
            for (int d = 0; d < 9; ++d) {
                const double x = (double)bf[cc * 9 + d];
                const int    b = (c * 9 + d) * 4;
                h0 = fma(x, Aw[b + 0], h0);
                h1 = fma(x, Aw[b + 1], h1);
                h2 = fma(x, Aw[b + 2], h2);
                h3 = fma(x, Aw[b + 3], h3);
            }
            // ---- parallel 15-threshold compare (T from SGPRs) ----
            const double* tp = Tw + c * 15;
            uint32_t mk = 0;
            mk |= (h0 > tp[0])  ?     1u : 0u;   // node 0  (level 0)
            mk |= (h1 > tp[1])  ?     2u : 0u;   // node 1  (level 1)
            mk |= (h1 > tp[2])  ?     4u : 0u;   // node 2
            mk |= (h2 > tp[3])  ?     8u : 0u;   // node 3  (level 2)
            mk |= (h2 > tp[4])  ?    16u : 0u;   // node 4
            mk |= (h2 > tp[5])  ?    32u : 0u;   // node 5
            mk |= (h2 > tp[6])  ?    64u : 0u;   // node 6
            mk |= (h3 > tp[7])  ?   128u : 0u;   // node 7  (level 3)
            mk |= (h3 > tp[8])  ?   256u : 0u;   // node 8
            mk |= (h3 > tp[9])  ?   512u : 0u;   // node 9
            mk |= (h3 > tp[10]) ?  1024u : 0u;   // node 10
            mk |= (h3 > tp[11]) ?  2048u : 0u;   // node 11
            mk |= (h3 > tp[12]) ?  4096u : 0u;   // node 12
            mk |= (h3 > tp[13]) ?  8192u : 0u;   // node 13
            mk |= (h3 > tp[14]) ? 16384u : 0u;   // node 14
            int p =       (int)(mk & 1u);
            p = 2 * p + (int)((mk >> (1 + p)) & 1u);
            p = 2 * p + (int)((mk >> (3 + p)) & 1u);
            p = 2 * p + (int)((mk >> (7 + p)) & 1u);

            // ---- gather cb c: 8 x ds_read_b128, 16-slot spread = 2-way free ----
            const uint4* colp = lut4 + (c << 4) + p;
            #pragma unroll
            for (int q = 0; q < 8; ++q) {
                const uint4 w = colp[q << 8];
                acc2[q * 4 + 0] = __hadd2(acc2[q * 4 + 0], *(const __half2*)&w.x);
                acc2[q * 4 + 1] = __hadd2(acc2[q * 4 + 1], *(const __half2*)&w.y);
                acc2[q * 4 + 2] = __hadd2(acc2[q * 4 + 2], *(const __half2*)&w.z);
                acc2[q * 4 + 3] = __hadd2(acc2[q * 4 + 3], *(const __half2*)&w.w);
            }
        }
    }

    // ---- epilogue: swizzled LDS transpose (measured 0 conflicts), 2x128 rows ----
    __syncthreads();                     // LUT dead
    float* sO = (float*)sBuf;            // [128 rows][64 m], 16B-chunk swizzle
    #pragma unroll
    for (int half = 0; half < 2; ++half) {
        if ((tid >> 7) == half) {        // wave-uniform branch (waves 0-1 / 2-3)
            const int r = tid & 127;
            #pragma unroll
            for (int ch = 0; ch < 16; ++ch) {
                const float4 v = make_float4(__low2float (acc2[2 * ch]),
                                             __high2float(acc2[2 * ch]),
                                             __low2float (acc2[2 * ch + 1]),
                                             __high2float(acc2[2 * ch + 1]));
                *(float4*)&sO[(r << 6) + ((ch ^ (r & 15)) << 2)] = v;
            }
        }
        __syncthreads();
        float4* op = (float4*)(out + (size_t)blockIdx.x * (256 * 64)
                                   + (size_t)half * (128 * 64));
        #pragma unroll
        for (int j = 0; j < 8; ++j) {    // 2048 float4 = 32 KiB, contiguous
            const int F  = tid + (j << 8);
            const int r2 = F >> 4;
            const int m2 = F & 15;
            op[F] = *(const float4*)&sO[(r2 << 6) + ((m2 ^ (r2 & 15)) << 2)];
        }
        __syncthreads();
    }
}

extern "C" void kernel_launch(void* const* d_in, const int* in_sizes, int n_in,
                              void* d_out, int out_size, void* d_ws, size_t ws_size,
                              hipStream_t stream) {
    const float* I = (const float*)d_in[0];
    const float* A = (const float*)d_in[1];
    const float* T = (const float*)d_in[2];
    const float* L = (const float*)d_in[3];
    float* outp = (float*)d_out;
    double* W = (double*)d_ws;           // 816 f64 = 6.5 KB

    halut_prep<<<1, 1024, 0, stream>>>(A, T, W);
    const int nblocks = NROWS / 256;     // 512 blocks x 256 threads, 1 thr/row
    halut_fwd<<<nblocks, 256, 0, stream>>>(I, W, L, outp);
}

// Round 10
// 27.382 us; speedup vs baseline: 1.5840x; 1.5840x over previous
//
#include <hip/hip_runtime.h>
#include <hip/hip_fp16.h>

// HalutMatmul forward on MI355X.
// Per row n: h[c][p] = sum_d I[n, c*9+d] * A[c][d][p]   (c=0..15, p=0..3)
//            code_c  = 4-level tree descent: bit_l = (h[c][l] > T[c*15 + node_l])
//            out[n][m] = sum_c L[m][c][code_c]
//
// Round-10: LDS-ledger attack. R3-R8 all ~30us because the per-CU LDS pipe ran
// ~590 instr/wave (~23us), 70% of it wave-redundant A/T broadcasts. Here:
//  - lane (g,c) holds codebook c's A (36 f32) + T (15 f32) in VGPRs, loaded
//    ONCE -> zero A/T LDS traffic in the loop.
//  - hash: 4 rows/pass (g=row, c=codebook) from a wave-private I tile staged
//    with fully-coalesced VMEM (also kills the 576B-strided load pattern);
//    stage loads issued early, written late (latency hides under hash).
//  - codes hand off via 4KB LDS byte array (16 wr + 1 rd per wave).
//  - gather + epilogue: lane=row, round-8 code verbatim (proven, ~free).
//  - f64 math identical order -> codes bit-identical, absmax 0.0039.

#define NROWS (1024 * 128)

__global__ __launch_bounds__(256, 2) void halut_fwd(
    const float* __restrict__ I,
    const float* __restrict__ A,
    const float* __restrict__ T,
    const float* __restrict__ L,
    float* __restrict__ out)
{
    // 32KB f16 LUT (reused as epilogue staging) + 4x9KB per-wave I tiles + 4KB codes
    __shared__ uint32_t sLut[8192];
    __shared__ float    sStage[4][2304];   // wave-private: 16 rows x 144 f32
    __shared__ uint8_t  sCodes[4096];      // [256 block-rows][16 c]

    const int tid  = threadIdx.x;
    const int w    = tid >> 6;
    const int lane = tid & 63;

    // ---- per-lane constants: lane (g,c) owns codebook cB ----
    const int cB = lane & 15;              // codebook (hash phase)
    const int g  = lane >> 4;              // row-in-pass (hash phase)
    float Af[36];
    {
        const float4* ap4 = (const float4*)(A + cB * 36);   // 144B-aligned
        #pragma unroll
        for (int i = 0; i < 9; ++i) {
            const float4 v = ap4[i];
            Af[4*i+0] = v.x; Af[4*i+1] = v.y; Af[4*i+2] = v.z; Af[4*i+3] = v.w;
        }
    }
    float Tf[15];
    #pragma unroll
    for (int j = 0; j < 15; ++j) Tf[j] = T[cB * 15 + j];

    // ---- stage f16 LUT: thread t owns column col = t (round-8 layout) ----
    {
        uint4* lut4 = (uint4*)sLut;
        #pragma unroll
        for (int q = 0; q < 8; ++q) {
            uint32_t wv[4];
            #pragma unroll
            for (int e = 0; e < 4; ++e) {
                const float fa = L[(8*q + 2*e)     * 256 + tid];
                const float fb = L[(8*q + 2*e + 1) * 256 + tid];
                wv[e] = ((uint32_t)__half_as_ushort(__float2half_rn(fb)) << 16)
                      |  (uint32_t)__half_as_ushort(__float2half_rn(fa));
            }
            lut4[q * 256 + tid] = make_uint4(wv[0], wv[1], wv[2], wv[3]);
        }
    }
    __syncthreads();   // only cross-wave dependency: LUT visible to all waves

    // ---- hash superphases: 4 x (stage 16 rows coalesced, 4 passes x 4 rows) ----
    const int wave_row0 = blockIdx.x * 256 + w * 64;   // global row base of wave
    const float4* Isrc = (const float4*)I;
    float4* st4 = (float4*)sStage[w];

    float4 nbuf[9];
    #pragma unroll
    for (int i = 0; i < 9; ++i)
        nbuf[i] = Isrc[(size_t)wave_row0 * 36 + i * 64 + lane];

    #pragma unroll
    for (int p16 = 0; p16 < 4; ++p16) {
        #pragma unroll
        for (int i = 0; i < 9; ++i) st4[i * 64 + lane] = nbuf[i];   // write-late
        if (p16 < 3) {                                               // issue-early
            #pragma unroll
            for (int i = 0; i < 9; ++i)
                nbuf[i] = Isrc[(size_t)(wave_row0 + (p16+1)*16) * 36 + i*64 + lane];
        }
        #pragma unroll
        for (int ps = 0; ps < 4; ++ps) {
            const int lr = ps * 4 + g;            // row 0..15 within chunk
            const float* xr = &sStage[w][lr * 144 + cB * 9];
            // f64 hash, same value/order as rounds 1-9 (codes bit-identical)
            double h0 = 0.0, h1 = 0.0, h2 = 0.0, h3 = 0.0;
            #pragma unroll
            for (int d = 0; d < 9; ++d) {
                const double x = (double)xr[d];
                h0 = fma(x, (double)Af[4*d+0], h0);
                h1 = fma(x, (double)Af[4*d+1], h1);
                h2 = fma(x, (double)Af[4*d+2], h2);
                h3 = fma(x, (double)Af[4*d+3], h3);
            }
            uint32_t mk = 0;
            mk |= (h0 > (double)Tf[0])  ?     1u : 0u;   // node 0  (level 0)
            mk |= (h1 > (double)Tf[1])  ?     2u : 0u;   // node 1  (level 1)
            mk |= (h1 > (double)Tf[2])  ?     4u : 0u;   // node 2
            mk |= (h2 > (double)Tf[3])  ?     8u : 0u;   // node 3  (level 2)
            mk |= (h2 > (double)Tf[4])  ?    16u : 0u;   // node 4
            mk |= (h2 > (double)Tf[5])  ?    32u : 0u;   // node 5
            mk |= (h2 > (double)Tf[6])  ?    64u : 0u;   // node 6
            mk |= (h3 > (double)Tf[7])  ?   128u : 0u;   // node 7  (level 3)
            mk |= (h3 > (double)Tf[8])  ?   256u : 0u;   // node 8
            mk |= (h3 > (double)Tf[9])  ?   512u : 0u;   // node 9
            mk |= (h3 > (double)Tf[10]) ?  1024u : 0u;   // node 10
            mk |= (h3 > (double)Tf[11]) ?  2048u : 0u;   // node 11
            mk |= (h3 > (double)Tf[12]) ?  4096u : 0u;   // node 12
            mk |= (h3 > (double)Tf[13]) ?  8192u : 0u;   // node 13
            mk |= (h3 > (double)Tf[14]) ? 16384u : 0u;   // node 14
            int p =       (int)(mk & 1u);
            p = 2 * p + (int)((mk >> (1 + p)) & 1u);
            p = 2 * p + (int)((mk >> (3 + p)) & 1u);
            p = 2 * p + (int)((mk >> (7 + p)) & 1u);
            sCodes[(w * 64 + p16 * 16 + lr) * 16 + cB] = (uint8_t)p;
        }
    }

    // ---- gather: lane = row (round-8 proven path) ----
    const uint4 cw = *(const uint4*)&sCodes[tid * 16];   // my row's 16 codes
    const uint32_t cd0 = cw.x, cd1 = cw.y, cd2 = cw.z, cd3 = cw.w;

    __half2 acc2[32];
    #pragma unroll
    for (int k = 0; k < 32; ++k) acc2[k] = __floats2half2_rn(0.f, 0.f);

    const uint4* lut4 = (const uint4*)sLut;
    #pragma unroll 4
    for (int c = 0; c < 16; ++c) {
        const uint32_t cdw = (c < 4) ? cd0 : (c < 8) ? cd1 : (c < 12) ? cd2 : cd3;
        const int p = (int)((cdw >> ((c & 3) * 8)) & 15u);
        const uint4* colp = lut4 + (c << 4) + p;
        #pragma unroll
        for (int q = 0; q < 8; ++q) {
            const uint4 wv = colp[q << 8];
            acc2[q*4+0] = __hadd2(acc2[q*4+0], *(const __half2*)&wv.x);
            acc2[q*4+1] = __hadd2(acc2[q*4+1], *(const __half2*)&wv.y);
            acc2[q*4+2] = __hadd2(acc2[q*4+2], *(const __half2*)&wv.z);
            acc2[q*4+3] = __hadd2(acc2[q*4+3], *(const __half2*)&wv.w);
        }
    }

    // ---- epilogue: swizzled LDS transpose (round-8 verbatim), 2 x 128 rows ----
    __syncthreads();                     // all gathers done; LUT region dead
    float* sO = (float*)sLut;            // [128 rows][64 m], 16B-chunk swizzle
    #pragma unroll
    for (int half = 0; half < 2; ++half) {
        if ((tid >> 7) == half) {        // wave-uniform branch
            const int r = tid & 127;
            #pragma unroll
            for (int ch = 0; ch < 16; ++ch) {
                const float4 v = make_float4(__low2float (acc2[2 * ch]),
                                             __high2float(acc2[2 * ch]),
                                             __low2float (acc2[2 * ch + 1]),
                                             __high2float(acc2[2 * ch + 1]));
                *(float4*)&sO[(r << 6) + ((ch ^ (r & 15)) << 2)] = v;
            }
        }
        __syncthreads();
        float4* op = (float4*)(out + (size_t)blockIdx.x * (256 * 64)
                                   + (size_t)half * (128 * 64));
        #pragma unroll
        for (int j = 0; j < 8; ++j) {    // 2048 float4 = 32 KiB, contiguous
            const int F  = tid + (j << 8);
            const int r2 = F >> 4;
            const int m2 = F & 15;
            op[F] = *(const float4*)&sO[(r2 << 6) + ((m2 ^ (r2 & 15)) << 2)];
        }
        __syncthreads();
    }
}

extern "C" void kernel_launch(void* const* d_in, const int* in_sizes, int n_in,
                              void* d_out, int out_size, void* d_ws, size_t ws_size,
                              hipStream_t stream) {
    const float* I = (const float*)d_in[0];
    const float* A = (const float*)d_in[1];
    const float* T = (const float*)d_in[2];
    const float* L = (const float*)d_in[3];
    float* outp = (float*)d_out;

    const int nblocks = NROWS / 256;   // 512 blocks x 256 threads
    halut_fwd<<<nblocks, 256, 0, stream>>>(I, A, T, L, outp);
}